// Round 8
// baseline (91.651 us; speedup 1.0000x reference)
//
#include <hip/hip_runtime.h>

// QuantumDMRGLayer: B=2048, L=196, M=16, NBL=10, pos_label=98 (fixed by setup).
// Round-8 = round-7 (sample-batched MFMA chain) + three fixes:
//   1. X pre-transposed to XT[col][sample] (prep grid, LDS tile) so the
//      per-site x loads are lane-coalesced instead of a 32-line gather.
//   2. Split accumulators: Da = Ahi*Bhi (independent) || Db = Ahi*Blo+Alo*Bhi
//      (2-chain) -> MFMA dep depth 2 instead of 3 per site (no TLP at 128
//      waves/1024 SIMDs, so dep latency is fully exposed).
//   3. v_perm_b32 packing for the bf16 hi/lo split (6 ops / value-pair),
//      branch-free 24x4 main loop + peeled left tail (sites 96,97).
// Structure recap: site update for 32 samples = D(32x32) = G(32x16) x
// V(16x32) via v_mfma_f32_32x32x16_bf16, split-bf16 for fp32-grade accuracy.
// G rows = [W0|W1] with bit2<->bit3 row permutation baked in at prep so each
// lane's D regs are exactly its own B-operand k-half: combine
// w[j] = x0*D[j] + x1*D[j+8] -> ZERO cross-lane ops in the whole chain.

typedef __attribute__((ext_vector_type(8))) short short8;
typedef __attribute__((ext_vector_type(16))) float floatx16;

#define GSITE_DW 512                 // dwords per site (hi 256 | lo 256)
#define GDIR_DW (100 * GSITE_DW)     // 100 sites per dir (2 pad)
#define STATE_DW (2 * GDIR_DW)       // float offset of state in d_ws
#define XT_DW (STATE_DW + 2 * 2048 * 16)  // float offset of XT in d_ws
// state: [dir][2048][16] floats; XT: [196][2048] float2

__device__ __forceinline__ unsigned bf16_rne(unsigned u) {
    return (u + 0x7FFFu + ((u >> 16) & 1u)) >> 16;
}

// ---- prep: G streams (blocks 0..199) + X transpose (blocks 200..647) ----
__global__ __launch_bounds__(256)
void prep_kernel(const float* __restrict__ AM, const float* __restrict__ X,
                 unsigned* __restrict__ WS)
{
    const int bid = blockIdx.x;
    if (bid < 200) {
        // lane l holds A-operand row r=l&31, k=8*(l>>5)+j. Stored value =
        // G[pi(r),k], pi = swap bits 2<->3.  left: G[(d,nn),k]=AM[p,d,k,nn];
        // right (site 193-p): G[(d,nn),k]=AM[193-p,d,nn,k].
        int t = bid * 256 + threadIdx.x;           // < 51200
        const int w    = t & 3;  t >>= 2;
        const int lane = t & 63; t >>= 6;
        const int p    = t % 100;
        const int dir  = t / 100;
        const int kb = (lane >> 5) << 3;
        const int r  = lane & 31;
        const int rr = (r & 0x13) | ((r & 4) << 1) | ((r & 8) >> 1);
        const int d = rr >> 4, nn = rr & 15;
        const int lim = dir ? 96 : 98;
        const int a = dir ? (193 - p) : p;
        const int k0 = kb + 2 * w;
        float g0 = 0.f, g1 = 0.f;
        if (p < lim) {
            const float* Ab = AM + a * 512 + d * 256;
            if (dir == 0) { g0 = Ab[k0 * 16 + nn]; g1 = Ab[(k0 + 1) * 16 + nn]; }
            else          { g0 = Ab[nn * 16 + k0]; g1 = Ab[nn * 16 + k0 + 1]; }
        }
        const unsigned h0 = bf16_rne(__float_as_uint(g0));
        const unsigned h1 = bf16_rne(__float_as_uint(g1));
        const float l0f = g0 - __uint_as_float(h0 << 16);
        const float l1f = g1 - __uint_as_float(h1 << 16);
        const unsigned lo0 = bf16_rne(__float_as_uint(l0f));
        const unsigned lo1 = bf16_rne(__float_as_uint(l1f));
        unsigned* gp = WS + (dir * 100 + p) * GSITE_DW;
        gp[lane * 4 + w]       = (h1 << 16) | h0;
        gp[256 + lane * 4 + w] = (lo1 << 16) | lo0;
    } else {
        // 32x32 float2 tile transpose: X[s][c] -> XT[c][s]
        __shared__ float2 tile[32][33];
        const int q  = bid - 200;                  // 0..447
        const int s0 = (q & 63) * 32;              // sample block
        const int c0 = (q >> 6) * 32;              // col block (0..6)
        const int t  = threadIdx.x;
        const int a = t & 31, b = t >> 5;
        const float2* X2 = (const float2*)X;
        float2* XT2 = (float2*)(WS) + (XT_DW >> 1);
#pragma unroll
        for (int k = 0; k < 4; ++k) {
            const int c = c0 + a, s = s0 + b + 8 * k;
            if (c < 196) tile[a][b + 8 * k] = X2[s * 196 + c];
        }
        __syncthreads();
#pragma unroll
        for (int k = 0; k < 4; ++k) {
            const int c = c0 + b + 8 * k, s = s0 + a;
            if (c < 196) XT2[c * 2048 + s] = tile[b + 8 * k][a];
        }
    }
}

// ---- main chain: 1 wave = 32 samples x 1 direction ----
__global__ __launch_bounds__(64, 1)
void chain_kernel(const float* __restrict__ AL,
                  const float* __restrict__ AR,
                  const unsigned* __restrict__ WS,
                  float* __restrict__ WST)
{
    const int lane = threadIdx.x;              // 0..63
    const int dir  = blockIdx.x & 1;
    const int s    = (blockIdx.x >> 1) * 32 + (lane & 31);
    const int kb   = (lane >> 5) << 3;         // this lane's k-half base
    const unsigned* Gb = WS + dir * GDIR_DW + lane * 4;
    const float2* Xt = (const float2*)(WS + XT_DW);  // [col][sample]

    float w[8];
    int4 vh4, vl4;
    auto pack = [&]() {                        // fp32 -> packed bf16 hi/lo
#pragma unroll
        for (int q = 0; q < 4; ++q) {
            const unsigned u0 = __float_as_uint(w[2 * q]);
            const unsigned u1 = __float_as_uint(w[2 * q + 1]);
            const float l0 = w[2 * q]     - __uint_as_float(u0 & 0xFFFF0000u);
            const float l1 = w[2 * q + 1] - __uint_as_float(u1 & 0xFFFF0000u);
            ((unsigned*)&vh4)[q] = __builtin_amdgcn_perm(u1, u0, 0x07060302u);
            ((unsigned*)&vl4)[q] = __builtin_amdgcn_perm(
                __float_as_uint(l1), __float_as_uint(l0), 0x07060302u);
        }
    };

    // ---- init bond vector: v[k] = x0*Ai[0][k] + x1*Ai[1][k] ----
    const float* Ai = dir ? AR : AL;
    const float2 xi = Xt[(dir ? 195 : 0) * 2048 + s];
#pragma unroll
    for (int j = 0; j < 8; ++j)
        w[j] = xi.x * Ai[kb + j] + xi.y * Ai[16 + kb + j];
    pack();

    // ---- 4-site register ring (G fragments + x pairs, all coalesced) ----
    int4 GH[4], GL[4];
    float2 xr[4];
#pragma unroll
    for (int i = 0; i < 4; ++i) {
        GH[i] = *(const int4*)(Gb + i * GSITE_DW);
        GL[i] = *(const int4*)(Gb + i * GSITE_DW + 256);
        xr[i] = Xt[(dir ? (194 - i) : (1 + i)) * 2048 + s];
    }

    auto site = [&](int j4, bool pf, int pn) {
        const short8 ah = *(short8*)&GH[j4];
        const short8 al = *(short8*)&GL[j4];
        const short8 bh = *(short8*)&vh4;
        const short8 bl = *(short8*)&vl4;
        floatx16 Da = {}, Db = {};
        Da = __builtin_amdgcn_mfma_f32_32x32x16_bf16(ah, bh, Da, 0, 0, 0);
        Db = __builtin_amdgcn_mfma_f32_32x32x16_bf16(ah, bl, Db, 0, 0, 0);
        Db = __builtin_amdgcn_mfma_f32_32x32x16_bf16(al, bh, Db, 0, 0, 0);
        const float2 xs = xr[j4];
        if (pf) {   // prefetch site pn into this ring slot
            GH[j4] = *(const int4*)(Gb + pn * GSITE_DW);
            GL[j4] = *(const int4*)(Gb + pn * GSITE_DW + 256);
            xr[j4] = Xt[(dir ? (194 - pn) : (1 + pn)) * 2048 + s];
        }
#pragma unroll
        for (int j = 0; j < 8; ++j)            // D[j]=W0, D[j+8]=W1, k=kb+j
            w[j] = fmaf(xs.x, Da[j] + Db[j], xs.y * (Da[j + 8] + Db[j + 8]));
        pack();
    };

    // ---- 24 chunks x 4 sites = 96 sites, branch-free ----
    for (int c = 0; c < 24; ++c) {
#pragma unroll
        for (int j4 = 0; j4 < 4; ++j4)
            site(j4, true, 4 * c + j4 + 4);    // pn <= 99, pad sites exist
    }
    // left chain has 2 extra sites (96, 97) already in ring slots 0, 1
    if (dir == 0) {
        site(0, false, 0);
        site(1, false, 0);
    }

    // ---- final state (fp32): comps kb..kb+7 of sample s ----
    float* st = WST + (dir * 2048 + s) * 16 + kb;
    *(float4*)(st)     = make_float4(w[0], w[1], w[2], w[3]);
    *(float4*)(st + 4) = make_float4(w[4], w[5], w[6], w[7]);
}

// ---- epilogue: out[s,l] = sum_{m,n} L[m,s] T[m,n,l] R[n,s] ----
__global__ __launch_bounds__(256)
void out_kernel(const float* __restrict__ T, const float* __restrict__ WST,
                float* __restrict__ OUT)
{
    __shared__ float sT[2560];
    const int tid = threadIdx.x;
    for (int k = tid; k < 640; k += 256)
        ((float4*)sT)[k] = ((const float4*)T)[k];
    __syncthreads();
    const int t = blockIdx.x * 256 + tid;      // < 20480
    const int s = t / 10, l = t - s * 10;
    const float* L = WST + s * 16;
    const float* R = WST + 2048 * 16 + s * 16;
    const float4 Ra = *(const float4*)(R);
    const float4 Rb = *(const float4*)(R + 4);
    const float4 Rc = *(const float4*)(R + 8);
    const float4 Rd = *(const float4*)(R + 12);
    float acc = 0.f;
#pragma unroll
    for (int m = 0; m < 16; ++m) {
        const float lm = L[m];
        const float* Tp = sT + m * 160 + l;
        acc = fmaf(lm * Ra.x, Tp[0],   acc);
        acc = fmaf(lm * Ra.y, Tp[10],  acc);
        acc = fmaf(lm * Ra.z, Tp[20],  acc);
        acc = fmaf(lm * Ra.w, Tp[30],  acc);
        acc = fmaf(lm * Rb.x, Tp[40],  acc);
        acc = fmaf(lm * Rb.y, Tp[50],  acc);
        acc = fmaf(lm * Rb.z, Tp[60],  acc);
        acc = fmaf(lm * Rb.w, Tp[70],  acc);
        acc = fmaf(lm * Rc.x, Tp[80],  acc);
        acc = fmaf(lm * Rc.y, Tp[90],  acc);
        acc = fmaf(lm * Rc.z, Tp[100], acc);
        acc = fmaf(lm * Rc.w, Tp[110], acc);
        acc = fmaf(lm * Rd.x, Tp[120], acc);
        acc = fmaf(lm * Rd.y, Tp[130], acc);
        acc = fmaf(lm * Rd.z, Tp[140], acc);
        acc = fmaf(lm * Rd.w, Tp[150], acc);
    }
    OUT[t] = acc;
}

extern "C" void kernel_launch(void* const* d_in, const int* in_sizes, int n_in,
                              void* d_out, int out_size, void* d_ws, size_t ws_size,
                              hipStream_t stream)
{
    const float* X  = (const float*)d_in[0];   // (2048,196,2)
    const float* AL = (const float*)d_in[1];   // (2,16)
    const float* AM = (const float*)d_in[2];   // (194,2,16,16)
    const float* AR = (const float*)d_in[3];   // (2,16)
    const float* T  = (const float*)d_in[4];   // (16,16,10)
    (void)in_sizes; (void)n_in; (void)out_size; (void)ws_size;
    unsigned* WS = (unsigned*)d_ws;            // G streams + state + XT
    float* WST   = (float*)d_ws + STATE_DW;
    float* OUT   = (float*)d_out;              // (2048,10)

    hipLaunchKernelGGL(prep_kernel,  dim3(648), dim3(256), 0, stream, AM, X, WS);
    hipLaunchKernelGGL(chain_kernel, dim3(128), dim3(64),  0, stream,
                       AL, AR, WS, WST);
    hipLaunchKernelGGL(out_kernel,   dim3(80),  dim3(256), 0, stream,
                       T, WST, OUT);
}

// Round 9
// 89.680 us; speedup vs baseline: 1.0220x; 1.0220x over previous
//
#include <hip/hip_runtime.h>

// QuantumDMRGLayer: B=2048, L=196, M=16, NBL=10, pos_label=98 (fixed by setup).
// Round-9 = round-7 structure (best so far, 87.5 us) + two targeted fixes:
//   1. REVERTED round-8's XT transpose (it added a 6.4 MB round-trip through
//      the 0xAA-poisoned ws + 448 prep blocks; the direct per-lane X gather
//      was already hidden by the 4-site prefetch ring -> round 8 regressed).
//   2. Prep kernel rewritten LDS-staged: one block per (dir,site), coalesced
//      2 KB load of the site matrix into LDS, scattered reads from LDS,
//      contiguous gp[threadIdx] stores (round-7 prep did per-lane 4 B global
//      reads at 64 B stride = 16x over-fetch).
//   Kept from round 8: split accumulators Da = Ahi*Bhi || Db = Ahi*Blo +
//   Alo*Bhi (MFMA dep depth 2, not 3 -- no TLP at 128 waves/1024 SIMDs so
//   dep latency is fully exposed) and v_perm_b32 bf16 packing.
// Structure recap: 1 wave = 32 samples x 1 direction; site update =
// D(32x32) = G(32x16) x V(16comps x 32samples) via v_mfma_f32_32x32x16_bf16,
// split-bf16 hi/lo for fp32-grade accuracy. G rows = [W0|W1] with a
// bit2<->bit3 row permutation baked in at prep so each lane's D registers
// are exactly its own B-operand k-half: combine w[j] = x0*D[j] + x1*D[j+8]
// -> ZERO cross-lane ops in the whole 98-site chain.

typedef __attribute__((ext_vector_type(8))) short short8;
typedef __attribute__((ext_vector_type(16))) float floatx16;

#define GSITE_DW 512                 // dwords per site (hi 256 | lo 256)
#define GDIR_DW (100 * GSITE_DW)     // 100 sites per dir (2 pad)
#define STATE_DW (2 * GDIR_DW)       // float offset of state in d_ws
// state: [dir][2048][16] floats

__device__ __forceinline__ unsigned bf16_rne(unsigned u) {
    return (u + 0x7FFFu + ((u >> 16) & 1u)) >> 16;
}

// ---- prep: build split-bf16, row-permuted G streams in d_ws ----
// Block = (dir, p). Lane l (=t>>2) holds A-operand row r=l&31 for k-half
// kb=8*(l>>5); w=t&3 covers k pairs. Stored value = G[pi(r),k], pi = swap
// bits 2<->3 of the low nibble (keeps d = bit4):
//   left  (site p):     G[(d,nn),k] = AM[p,     d, k, nn]
//   right (site 193-p): G[(d,nn),k] = AM[193-p, d, nn, k]
__global__ __launch_bounds__(256)
void prep_kernel(const float* __restrict__ AM, unsigned* __restrict__ WS)
{
    const int bid = blockIdx.x;                // 0..199
    const int dir = bid / 100;
    const int p   = bid % 100;
    const int lim = dir ? 96 : 98;
    const int a   = dir ? (193 - p) : p;
    const int t   = threadIdx.x;

    __shared__ float sM[512];                  // one site: [d][16][16]
    if (p < lim)
        ((float2*)sM)[t] = ((const float2*)(AM + a * 512))[t];
    else
        ((float2*)sM)[t] = make_float2(0.f, 0.f);   // pad sites -> zero
    __syncthreads();

    const int w    = t & 3;
    const int lane = t >> 2;
    const int kb = (lane >> 5) << 3;
    const int r  = lane & 31;
    const int rr = (r & 0x13) | ((r & 4) << 1) | ((r & 8) >> 1);  // pi(r)
    const int d = rr >> 4, nn = rr & 15;
    const int k0 = kb + 2 * w;

    float g0, g1;
    if (dir == 0) { g0 = sM[d * 256 + k0 * 16 + nn];
                    g1 = sM[d * 256 + (k0 + 1) * 16 + nn]; }
    else          { g0 = sM[d * 256 + nn * 16 + k0];
                    g1 = sM[d * 256 + nn * 16 + k0 + 1]; }

    const unsigned h0 = bf16_rne(__float_as_uint(g0));
    const unsigned h1 = bf16_rne(__float_as_uint(g1));
    const float l0f = g0 - __uint_as_float(h0 << 16);
    const float l1f = g1 - __uint_as_float(h1 << 16);
    const unsigned lo0 = bf16_rne(__float_as_uint(l0f));
    const unsigned lo1 = bf16_rne(__float_as_uint(l1f));

    unsigned* gp = WS + (dir * 100 + p) * GSITE_DW;
    gp[t]       = (h1 << 16) | h0;             // contiguous 1 KB store
    gp[256 + t] = (lo1 << 16) | lo0;           // contiguous 1 KB store
}

// ---- main chain: 1 wave = 32 samples x 1 direction ----
__global__ __launch_bounds__(64, 1)
void chain_kernel(const float* __restrict__ X,
                  const float* __restrict__ AL,
                  const float* __restrict__ AR,
                  const unsigned* __restrict__ WS,
                  float* __restrict__ WST)
{
    const int lane = threadIdx.x;              // 0..63
    const int dir  = blockIdx.x & 1;
    const int s    = (blockIdx.x >> 1) * 32 + (lane & 31);
    const int kb   = (lane >> 5) << 3;         // this lane's k-half base
    const float* Xs = X + s * 392;
    const unsigned* Gb = WS + dir * GDIR_DW + lane * 4;

    float w[8];
    int4 vh4, vl4;
    auto pack = [&]() {                        // fp32 -> packed bf16 hi/lo
#pragma unroll
        for (int q = 0; q < 4; ++q) {
            const unsigned u0 = __float_as_uint(w[2 * q]);
            const unsigned u1 = __float_as_uint(w[2 * q + 1]);
            const float l0 = w[2 * q]     - __uint_as_float(u0 & 0xFFFF0000u);
            const float l1 = w[2 * q + 1] - __uint_as_float(u1 & 0xFFFF0000u);
            ((unsigned*)&vh4)[q] = __builtin_amdgcn_perm(u1, u0, 0x07060302u);
            ((unsigned*)&vl4)[q] = __builtin_amdgcn_perm(
                __float_as_uint(l1), __float_as_uint(l0), 0x07060302u);
        }
    };

    // ---- init bond vector: v[k] = x0*Ai[0][k] + x1*Ai[1][k] ----
    const float* Ai = dir ? AR : AL;
    const float2 xi = *(const float2*)(Xs + (dir ? 390 : 0));
#pragma unroll
    for (int j = 0; j < 8; ++j)
        w[j] = xi.x * Ai[kb + j] + xi.y * Ai[16 + kb + j];
    pack();

    // ---- 4-site register ring (G fragments + x pairs) ----
    int4 GH[4], GL[4];
    float2 xr[4];
#pragma unroll
    for (int i = 0; i < 4; ++i) {
        GH[i] = *(const int4*)(Gb + i * GSITE_DW);
        GL[i] = *(const int4*)(Gb + i * GSITE_DW + 256);
        xr[i] = *(const float2*)(Xs + (dir ? (388 - 2 * i) : (2 + 2 * i)));
    }

    auto site = [&](int j4, bool pf, int pn) {
        const short8 ah = *(short8*)&GH[j4];
        const short8 al = *(short8*)&GL[j4];
        const short8 bh = *(short8*)&vh4;
        const short8 bl = *(short8*)&vl4;
        floatx16 Da = {}, Db = {};
        Da = __builtin_amdgcn_mfma_f32_32x32x16_bf16(ah, bh, Da, 0, 0, 0);
        Db = __builtin_amdgcn_mfma_f32_32x32x16_bf16(ah, bl, Db, 0, 0, 0);
        Db = __builtin_amdgcn_mfma_f32_32x32x16_bf16(al, bh, Db, 0, 0, 0);
        const float2 xs = xr[j4];
        if (pf) {   // prefetch site pn into this ring slot (4 sites ahead)
            GH[j4] = *(const int4*)(Gb + pn * GSITE_DW);
            GL[j4] = *(const int4*)(Gb + pn * GSITE_DW + 256);
            xr[j4] = *(const float2*)(Xs + (dir ? (388 - 2 * pn)
                                                : (2 + 2 * pn)));
        }
#pragma unroll
        for (int j = 0; j < 8; ++j)            // D[j]=W0, D[j+8]=W1, k=kb+j
            w[j] = fmaf(xs.x, Da[j] + Db[j], xs.y * (Da[j + 8] + Db[j + 8]));
        pack();
    };

    // ---- 24 chunks x 4 sites = 96 sites, branch-free ----
    for (int c = 0; c < 24; ++c) {
#pragma unroll
        for (int j4 = 0; j4 < 4; ++j4)
            site(j4, true, 4 * c + j4 + 4);    // pn <= 99, pad sites exist
    }
    // left chain has 2 extra sites (96, 97) already in ring slots 0, 1
    if (dir == 0) {
        site(0, false, 0);
        site(1, false, 0);
    }

    // ---- final state (fp32): comps kb..kb+7 of sample s ----
    float* st = WST + (dir * 2048 + s) * 16 + kb;
    *(float4*)(st)     = make_float4(w[0], w[1], w[2], w[3]);
    *(float4*)(st + 4) = make_float4(w[4], w[5], w[6], w[7]);
}

// ---- epilogue: out[s,l] = sum_{m,n} L[m,s] T[m,n,l] R[n,s] ----
__global__ __launch_bounds__(256)
void out_kernel(const float* __restrict__ T, const float* __restrict__ WST,
                float* __restrict__ OUT)
{
    __shared__ float sT[2560];
    const int tid = threadIdx.x;
    for (int k = tid; k < 640; k += 256)
        ((float4*)sT)[k] = ((const float4*)T)[k];
    __syncthreads();
    const int t = blockIdx.x * 256 + tid;      // < 20480
    const int s = t / 10, l = t - s * 10;
    const float* L = WST + s * 16;
    const float* R = WST + 2048 * 16 + s * 16;
    const float4 Ra = *(const float4*)(R);
    const float4 Rb = *(const float4*)(R + 4);
    const float4 Rc = *(const float4*)(R + 8);
    const float4 Rd = *(const float4*)(R + 12);
    float acc = 0.f;
#pragma unroll
    for (int m = 0; m < 16; ++m) {
        const float lm = L[m];
        const float* Tp = sT + m * 160 + l;
        acc = fmaf(lm * Ra.x, Tp[0],   acc);
        acc = fmaf(lm * Ra.y, Tp[10],  acc);
        acc = fmaf(lm * Ra.z, Tp[20],  acc);
        acc = fmaf(lm * Ra.w, Tp[30],  acc);
        acc = fmaf(lm * Rb.x, Tp[40],  acc);
        acc = fmaf(lm * Rb.y, Tp[50],  acc);
        acc = fmaf(lm * Rb.z, Tp[60],  acc);
        acc = fmaf(lm * Rb.w, Tp[70],  acc);
        acc = fmaf(lm * Rc.x, Tp[80],  acc);
        acc = fmaf(lm * Rc.y, Tp[90],  acc);
        acc = fmaf(lm * Rc.z, Tp[100], acc);
        acc = fmaf(lm * Rc.w, Tp[110], acc);
        acc = fmaf(lm * Rd.x, Tp[120], acc);
        acc = fmaf(lm * Rd.y, Tp[130], acc);
        acc = fmaf(lm * Rd.z, Tp[140], acc);
        acc = fmaf(lm * Rd.w, Tp[150], acc);
    }
    OUT[t] = acc;
}

extern "C" void kernel_launch(void* const* d_in, const int* in_sizes, int n_in,
                              void* d_out, int out_size, void* d_ws, size_t ws_size,
                              hipStream_t stream)
{
    const float* X  = (const float*)d_in[0];   // (2048,196,2)
    const float* AL = (const float*)d_in[1];   // (2,16)
    const float* AM = (const float*)d_in[2];   // (194,2,16,16)
    const float* AR = (const float*)d_in[3];   // (2,16)
    const float* T  = (const float*)d_in[4];   // (16,16,10)
    (void)in_sizes; (void)n_in; (void)out_size; (void)ws_size;
    unsigned* WS = (unsigned*)d_ws;            // G streams: 400 KB
    float* WST   = (float*)d_ws + STATE_DW;    // states: 256 KB
    float* OUT   = (float*)d_out;              // (2048,10)

    hipLaunchKernelGGL(prep_kernel,  dim3(200), dim3(256), 0, stream, AM, WS);
    hipLaunchKernelGGL(chain_kernel, dim3(128), dim3(64),  0, stream,
                       X, AL, AR, WS, WST);
    hipLaunchKernelGGL(out_kernel,   dim3(80),  dim3(256), 0, stream,
                       T, WST, OUT);
}